// Round 7
// baseline (265.833 us; speedup 1.0000x reference)
//
#include <hip/hip_runtime.h>
#include <hip/hip_bf16.h>
#include <cstdint>

// ---------------------------------------------------------------------------
// HierDSFeedForward: LN -> shared SwiGLU FFN + hierarchical top-2 MoE
// S=8192 tokens, C=512, H=1024, G=2 groups x EG=4 experts, K=2
// R6: revert gemm2 to R4 (dbuf regressed, m99/m100-style); gemm1 widened to
//     128-h-cols/block (2x MFMA per staged byte); dispatches 8->4 (cvt fused
//     into ln_gate, memset+build+prefix merged into one-block route_build).
// ---------------------------------------------------------------------------

typedef __bf16 bf16x8 __attribute__((ext_vector_type(8)));
typedef __bf16 bf16x4 __attribute__((ext_vector_type(4)));
typedef float  f32x4  __attribute__((ext_vector_type(4)));

#define S_TOT 8192
#define C_DIM 512
#define H_DIM 1024
// max expert M-tiles: sum_e ceil(cnt_e/128) <= 16384/128 + 8 = 136
#define MAX_ETILES 136

// async global->LDS, 16B per lane. Per-lane GLOBAL address may scatter;
// LDS dest is wave-uniform base + lane*16.
__device__ __forceinline__ void gload_lds16(const void* g, void* l) {
  __builtin_amdgcn_global_load_lds(
      (__attribute__((address_space(1))) void*)(void*)(g),
      (__attribute__((address_space(3))) void*)(l),
      16, 0, 0);
}

// ---------------------------------------------------------------------------
// Fused LayerNorm/gating (blocks 0..2047) + weight cvt (blocks 2048..8703).
// LN part: wave-per-token, 4 tokens/block, lane owns 8 contiguous channels.
__global__ __launch_bounds__(256) void ln_gate_cvt(
    const float* __restrict__ x,
    const float* __restrict__ ln_scale, const float* __restrict__ ln_bias,
    const float* __restrict__ ggw,   // [2,512]
    const float* __restrict__ egw,   // [8,512]
    const float* __restrict__ gb,    // [2]
    const float* __restrict__ eb,    // [8]
    const float* __restrict__ sob,   // [512]
    const float* __restrict__ eob,   // [8,512]
    const float* __restrict__ siw, const float* __restrict__ eiw,
    const float* __restrict__ eow, const float* __restrict__ sow,
    __bf16* __restrict__ w1,         // [4096,512] bf16
    __bf16* __restrict__ w2,         // [9,512,1024] bf16
    __bf16* __restrict__ lnb,        // [8192,512] bf16 LN output
    float* __restrict__ comb,        // [8192,8] dense top-2 weights
    float* __restrict__ out)         // [8192,512] init: biases
{
  if (blockIdx.x >= 2048) {
    // ---- weight conversion: 4 elems/thread ----
    const int i = ((blockIdx.x - 2048) * 256 + threadIdx.x) * 4;
    const float* src;
    __bf16* dst;
    if (i < 2097152) {  // w1 = [siw | eiw]
      src = (i < 1048576) ? (siw + i) : (eiw + (i - 1048576));
      dst = w1 + i;
    } else {            // w2 = [eow | sow]
      const int j = i - 2097152;
      src = (j < 4194304) ? (eow + j) : (sow + (j - 4194304));
      dst = w2 + j;
    }
    float4 v = *(const float4*)src;
    bf16x4 o;
    o[0] = (__bf16)v.x; o[1] = (__bf16)v.y; o[2] = (__bf16)v.z; o[3] = (__bf16)v.w;
    *(bf16x4*)dst = o;
    return;
  }

  // ---- LN + gating ----
  const int wave = threadIdx.x >> 6, lane = threadIdx.x & 63;
  const int s = blockIdx.x * 4 + wave;
  const size_t rowb = (size_t)s * C_DIM;
  const int c0 = lane * 8;

  const float4 va = *(const float4*)(x + rowb + c0);
  const float4 vb = *(const float4*)(x + rowb + c0 + 4);
  float v[8] = {va.x, va.y, va.z, va.w, vb.x, vb.y, vb.z, vb.w};

  float sum = 0.f;
#pragma unroll
  for (int j = 0; j < 8; j++) sum += v[j];
#pragma unroll
  for (int o = 1; o < 64; o <<= 1) sum += __shfl_xor(sum, o, 64);
  const float mu = sum * (1.0f / 512.0f);

  float sq = 0.f;
#pragma unroll
  for (int j = 0; j < 8; j++) { const float d = v[j] - mu; sq += d * d; }
#pragma unroll
  for (int o = 1; o < 64; o <<= 1) sq += __shfl_xor(sq, o, 64);
  const float rs = rsqrtf(sq * (1.0f / 512.0f) + 1e-5f);

  const float4 sa = *(const float4*)(ln_scale + c0);
  const float4 sb = *(const float4*)(ln_scale + c0 + 4);
  const float4 ba = *(const float4*)(ln_bias + c0);
  const float4 bb = *(const float4*)(ln_bias + c0 + 4);
  const float sc[8] = {sa.x, sa.y, sa.z, sa.w, sb.x, sb.y, sb.z, sb.w};
  const float bi[8] = {ba.x, ba.y, ba.z, ba.w, bb.x, bb.y, bb.z, bb.w};

  float y[8];
  bf16x8 yb;
#pragma unroll
  for (int j = 0; j < 8; j++) {
    y[j] = (v[j] - mu) * rs * sc[j] + bi[j];
    yb[j] = (__bf16)y[j];
  }
  *(bf16x8*)(lnb + rowb + c0) = yb;

  double lg[10];
#pragma unroll
  for (int r = 0; r < 10; r++) {
    const float* W = (r < 2) ? (ggw + r * C_DIM + c0) : (egw + (r - 2) * C_DIM + c0);
    const float4 wa = *(const float4*)(W);
    const float4 wb = *(const float4*)(W + 4);
    const float w[8] = {wa.x, wa.y, wa.z, wa.w, wb.x, wb.y, wb.z, wb.w};
    double p = 0.0;
#pragma unroll
    for (int j = 0; j < 8; j++) p += (double)y[j] * (double)w[j];
    lg[r] = p;
  }
#pragma unroll
  for (int o = 1; o < 64; o <<= 1) {
#pragma unroll
    for (int r = 0; r < 10; r++) lg[r] += __shfl_xor(lg[r], o, 64);
  }

  const double g0 = lg[0] + (double)gb[0], g1 = lg[1] + (double)gb[1];
  const int g = (g1 > g0) ? 1 : 0;
  double el[4], mx = -1e300;
#pragma unroll
  for (int j = 0; j < 4; j++) {
    el[j] = lg[2 + g * 4 + j] + (double)eb[g * 4 + j];
    if (el[j] > mx) mx = el[j];
  }
  double pr[4], ps = 0.0;
#pragma unroll
  for (int j = 0; j < 4; j++) { pr[j] = exp(el[j] - mx); ps += pr[j]; }
  int i0 = 0;
#pragma unroll
  for (int j = 1; j < 4; j++) if (pr[j] > pr[i0]) i0 = j;
  int i1 = -1;
#pragma unroll
  for (int j = 0; j < 4; j++) {
    if (j == i0) continue;
    if (i1 < 0 || pr[j] > pr[i1]) i1 = j;
  }
  const double p0 = pr[i0] / ps, p1 = pr[i1] / ps;
  const double nrm = p0 + p1 + 1e-8;
  const int e0 = g * 4 + i0, e1 = g * 4 + i1;
  const float w0 = (float)(p0 / nrm), w1v = (float)(p1 / nrm);

  if (lane < 8)
    comb[(size_t)s * 8 + lane] = (lane == e0) ? w0 : ((lane == e1) ? w1v : 0.0f);

  const float* eb0 = eob + e0 * C_DIM + c0;
  const float* eb1 = eob + e1 * C_DIM + c0;
  float4 oa, ob;
  {
    const float4 za = *(const float4*)(sob + c0);
    const float4 zb = *(const float4*)(sob + c0 + 4);
    const float4 ea = *(const float4*)(eb0);
    const float4 ebv = *(const float4*)(eb0 + 4);
    const float4 fa = *(const float4*)(eb1);
    const float4 fb = *(const float4*)(eb1 + 4);
    oa.x = za.x + ea.x + fa.x; oa.y = za.y + ea.y + fa.y;
    oa.z = za.z + ea.z + fa.z; oa.w = za.w + ea.w + fa.w;
    ob.x = zb.x + ebv.x + fb.x; ob.y = zb.y + ebv.y + fb.y;
    ob.z = zb.z + ebv.z + fb.z; ob.w = zb.w + ebv.w + fb.w;
  }
  *(float4*)(out + rowb + c0) = oa;
  *(float4*)(out + rowb + c0 + 4) = ob;
}

// ---------------------------------------------------------------------------
// Single-block routing build: replaces memset+build_lists+prefix_tiles.
// 1024 threads x 8 tokens; LDS-atomic histogram; writes cnt, off, tok.
__global__ __launch_bounds__(1024) void route_build(
    const float* __restrict__ comb, int* __restrict__ cnt,
    int* __restrict__ tok, int* __restrict__ off) {
  __shared__ int lcnt[8];
  const int tid = threadIdx.x;
  if (tid < 8) lcnt[tid] = 0;
  __syncthreads();
  int e0v[8], e1v[8], p0v[8], p1v[8];
#pragma unroll
  for (int t = 0; t < 8; t++) {
    const int s = t * 1024 + tid;
    const float4 ca = *(const float4*)(comb + (size_t)s * 8);
    const float4 cb = *(const float4*)(comb + (size_t)s * 8 + 4);
    const float cr[8] = {ca.x, ca.y, ca.z, ca.w, cb.x, cb.y, cb.z, cb.w};
    int e0 = -1, e1 = -1;
#pragma unroll
    for (int j = 0; j < 8; j++) {
      if (cr[j] != 0.0f) { if (e0 < 0) e0 = j; else e1 = j; }
    }
    e0v[t] = e0; e1v[t] = e1;
    p0v[t] = atomicAdd(&lcnt[e0], 1);
    p1v[t] = (e1 >= 0) ? atomicAdd(&lcnt[e1], 1) : 0;
  }
  __syncthreads();
  if (tid < 8) cnt[tid] = lcnt[tid];
  if (tid == 0) {
    int acc = 0;
#pragma unroll
    for (int e = 0; e < 8; e++) { off[e] = acc; acc += (lcnt[e] + 127) >> 7; }
    off[8] = acc;
  }
#pragma unroll
  for (int t = 0; t < 8; t++) {
    const int s = t * 1024 + tid;
    tok[e0v[t] * S_TOT + p0v[t]] = s;
    if (e1v[t] >= 0) tok[e1v[t] * S_TOT + p1v[t]] = s;
  }
}

// ---------------------------------------------------------------------------
// GEMM1 + fused SwiGLU, 128(M) x 128(h-cols) tile, BK=64 two-panel.
// A = ln_bf16 [8192,512]; W1 = [4096,512] (rows: 0..1023 shared-a,
// 1024..2047 shared-b, 2048..3071 expert-a, 3072..4095 expert-b).
// Per BK=64 iteration: 64 MFMA/wave vs 12 staging gloads/wave (2x the
// MFMA:stage ratio of the 64-wide tile). Writes silu(a)*b to H
// [8192,2048] bf16 (cols 0..1023 = h_shared, 1024..2047 = h_expert).
__global__ __launch_bounds__(256) void gemm1_swiglu(
    const __bf16* __restrict__ A,
    const __bf16* __restrict__ W1,
    __bf16* __restrict__ H)
{
  constexpr int K = C_DIM;  // 512
  __shared__ __bf16 As[2 * 128 * 32];    // [panel][row][32]
  __shared__ __bf16 Bas[2 * 128 * 32];
  __shared__ __bf16 Bbs[2 * 128 * 32];

  const int m0 = blockIdx.x * 128;
  const int nh = blockIdx.y * 128;               // h-col base
  const int arow0 = nh + (nh < 1024 ? 0 : 1024); // tile never straddles 1024
  const int brow0 = arow0 + 1024;

  const int tid = threadIdx.x, wave = tid >> 6, lane = tid & 63;
  const int wrow = wave >> 1, wcol = wave & 1;
  const int lr16 = lane >> 2;
  const int lc   = (lane & 3) * 8;
  const int fm   = lane & 15;
  const int fq   = (lane >> 4) * 8;

  // staging pointers: this wave owns rows wave*32 + {0,16} of each 128-row set
  const __bf16* a0  = A  + (size_t)(m0 + wave * 32 + lr16) * K + lc;
  const __bf16* a1  = a0 + (size_t)16 * K;
  const __bf16* pa0 = W1 + (size_t)(arow0 + wave * 32 + lr16) * K + lc;
  const __bf16* pa1 = pa0 + (size_t)16 * K;
  const __bf16* pb0 = W1 + (size_t)(brow0 + wave * 32 + lr16) * K + lc;
  const __bf16* pb1 = pb0 + (size_t)16 * K;
  const int sA0 = wave * 1024;   // (wave*32)*32
  const int sA1 = sA0 + 512;

  f32x4 acca[4][4] = {};
  f32x4 accb[4][4] = {};

  for (int k0 = 0; k0 < K; k0 += 64) {
    gload_lds16(a0 + k0,       As + sA0);
    gload_lds16(a0 + k0 + 32,  As + 4096 + sA0);
    gload_lds16(a1 + k0,       As + sA1);
    gload_lds16(a1 + k0 + 32,  As + 4096 + sA1);
    gload_lds16(pa0 + k0,      Bas + sA0);
    gload_lds16(pa0 + k0 + 32, Bas + 4096 + sA0);
    gload_lds16(pa1 + k0,      Bas + sA1);
    gload_lds16(pa1 + k0 + 32, Bas + 4096 + sA1);
    gload_lds16(pb0 + k0,      Bbs + sA0);
    gload_lds16(pb0 + k0 + 32, Bbs + 4096 + sA0);
    gload_lds16(pb1 + k0,      Bbs + sA1);
    gload_lds16(pb1 + k0 + 32, Bbs + 4096 + sA1);
    __syncthreads();

#pragma unroll
    for (int kc = 0; kc < 2; kc++) {
      bf16x8 af[4], ba[4], bb[4];
#pragma unroll
      for (int mi = 0; mi < 4; mi++)
        af[mi] = *(const bf16x8*)&As[kc * 4096 + (wrow * 64 + mi * 16 + fm) * 32 + fq];
#pragma unroll
      for (int ni = 0; ni < 4; ni++) {
        const int r = (wcol * 64 + ni * 16 + fm) * 32 + fq;
        ba[ni] = *(const bf16x8*)&Bas[kc * 4096 + r];
        bb[ni] = *(const bf16x8*)&Bbs[kc * 4096 + r];
      }
#pragma unroll
      for (int mi = 0; mi < 4; mi++) {
#pragma unroll
        for (int ni = 0; ni < 4; ni++) {
          acca[mi][ni] = __builtin_amdgcn_mfma_f32_16x16x32_bf16(af[mi], ba[ni], acca[mi][ni], 0, 0, 0);
          accb[mi][ni] = __builtin_amdgcn_mfma_f32_16x16x32_bf16(af[mi], bb[ni], accb[mi][ni], 0, 0, 0);
        }
      }
    }
    __syncthreads();
  }

  // epilogue: silu(a) * b -> bf16
#pragma unroll
  for (int mi = 0; mi < 4; mi++) {
    const int row0 = m0 + wrow * 64 + mi * 16 + ((lane >> 4) << 2);
#pragma unroll
    for (int ni = 0; ni < 4; ni++) {
      const int c = nh + wcol * 64 + ni * 16 + fm;
#pragma unroll
      for (int r = 0; r < 4; r++) {
        const float a = acca[mi][ni][r];
        const float b = accb[mi][ni][r];
        const float sv = a / (1.0f + __expf(-a));
        H[(size_t)(row0 + r) * (2 * H_DIM) + c] = (__bf16)(sv * b);
      }
    }
  }
}

// ---------------------------------------------------------------------------
// Unified GEMM2 over compacted expert tiles + dense shared tiles.
// R4 form (measured best): BK=64 two-panel, single buffer, 2 barriers/iter.
// blockIdx.x in [0, off[8])        : expert tiles, gathered A rows
// blockIdx.x in [off[8], off[8]+64): shared tiles, identity rows
// Epilogue: atomicAdd(out[token]) (out pre-init with biases).
__global__ __launch_bounds__(256) void gemm2_moe(
    const __bf16* __restrict__ Hb,   // [8192, 2048]
    const __bf16* __restrict__ W2,   // [9, 512, 1024] (8 experts + shared)
    const float* __restrict__ comb,  // [8192, 8]
    const int* __restrict__ cnt,     // [8]
    const int* __restrict__ tok,     // [8, 8192]
    const int* __restrict__ off,     // [9]
    float* __restrict__ out)         // [8192, 512]
{
  constexpr int K = H_DIM;  // 1024
  __shared__ __bf16 As[2 * 128 * 32];   // [panel][row][32]
  __shared__ __bf16 Bs[2 * 128 * 32];
  __shared__ int tokLDS[128];

  const int g = blockIdx.x;
  const int T = off[8];
  int e, m0;
  if (g < T) {
    e = 0;
    while (e < 7 && g >= off[e + 1]) e++;
    m0 = (g - off[e]) * 128;
  } else if (g < T + 64) {
    e = 8;
    m0 = (g - T) * 128;
  } else {
    return;
  }
  const int cnt_e = (e == 8) ? S_TOT : cnt[e];
  const int n0 = blockIdx.y * 128;
  const __bf16* Bw = W2 + (size_t)e * C_DIM * H_DIM;
  const int abase = (e == 8) ? 0 : H_DIM;

  const int tid = threadIdx.x, wave = tid >> 6, lane = tid & 63;
  const int wrow = wave >> 1, wcol = wave & 1;
  const int lr16 = lane >> 2;
  const int lc   = (lane & 3) * 8;
  const int fm   = lane & 15;
  const int fq   = (lane >> 4) * 8;

  if (tid < 128) {
    const int r = m0 + tid;
    tokLDS[tid] = (e == 8) ? r : ((r < cnt_e) ? tok[e * S_TOT + r] : -1);
  }
  __syncthreads();

  const int row0 = wave * 32 + lr16;
  const int t0 = tokLDS[row0], t1 = tokLDS[row0 + 16];
  const __bf16* a0 = Hb + abase + (size_t)(t0 < 0 ? 0 : t0) * (2 * H_DIM) + lc;
  const __bf16* a1 = Hb + abase + (size_t)(t1 < 0 ? 0 : t1) * (2 * H_DIM) + lc;
  const __bf16* b0 = Bw + (size_t)(n0 + wave * 32 + lr16) * K + lc;
  const __bf16* b1 = Bw + (size_t)(n0 + wave * 32 + 16 + lr16) * K + lc;

  const int sA0 = wave * 1024;   // (wave*32)*32
  const int sA1 = sA0 + 512;

  f32x4 acc[4][4] = {};

  for (int k0 = 0; k0 < K; k0 += 64) {
    gload_lds16(a0 + k0,      As + sA0);
    gload_lds16(a0 + k0 + 32, As + 4096 + sA0);
    gload_lds16(a1 + k0,      As + sA1);
    gload_lds16(a1 + k0 + 32, As + 4096 + sA1);
    gload_lds16(b0 + k0,      Bs + sA0);
    gload_lds16(b0 + k0 + 32, Bs + 4096 + sA0);
    gload_lds16(b1 + k0,      Bs + sA1);
    gload_lds16(b1 + k0 + 32, Bs + 4096 + sA1);
    __syncthreads();

#pragma unroll
    for (int kc = 0; kc < 2; kc++) {
      bf16x8 af[4], bf[4];
#pragma unroll
      for (int mi = 0; mi < 4; mi++)
        af[mi] = *(const bf16x8*)&As[kc * 4096 + (wrow * 64 + mi * 16 + fm) * 32 + fq];
#pragma unroll
      for (int ni = 0; ni < 4; ni++)
        bf[ni] = *(const bf16x8*)&Bs[kc * 4096 + (wcol * 64 + ni * 16 + fm) * 32 + fq];
#pragma unroll
      for (int mi = 0; mi < 4; mi++)
#pragma unroll
        for (int ni = 0; ni < 4; ni++)
          acc[mi][ni] = __builtin_amdgcn_mfma_f32_16x16x32_bf16(af[mi], bf[ni], acc[mi][ni], 0, 0, 0);
    }
    __syncthreads();
  }

#pragma unroll
  for (int mi = 0; mi < 4; mi++) {
    const int rbase = wrow * 64 + mi * 16 + ((lane >> 4) << 2);
#pragma unroll
    for (int r = 0; r < 4; r++) {
      const int token = tokLDS[rbase + r];
      if (token >= 0) {
        const float scale = (e == 8) ? 1.0f : comb[(size_t)token * 8 + e];
#pragma unroll
        for (int ni = 0; ni < 4; ni++) {
          const int c = n0 + wcol * 64 + ni * 16 + fm;
          atomicAdd(&out[(size_t)token * C_DIM + c], scale * acc[mi][ni][r]);
        }
      }
    }
  }
}

// ---------------------------------------------------------------------------
extern "C" void kernel_launch(void* const* d_in, const int* in_sizes, int n_in,
                              void* d_out, int out_size, void* d_ws, size_t ws_size,
                              hipStream_t stream) {
  const float* x    = (const float*)d_in[0];
  const float* lns  = (const float*)d_in[1];
  const float* lnbi = (const float*)d_in[2];
  const float* siw  = (const float*)d_in[3];   // [2048,512]
  const float* sow  = (const float*)d_in[4];   // [512,1024]
  const float* sob  = (const float*)d_in[5];   // [512]
  const float* eiw  = (const float*)d_in[6];   // [2048,512]
  const float* eow  = (const float*)d_in[7];   // [8,512,1024]
  const float* eob  = (const float*)d_in[8];   // [8,512]
  const float* ggw  = (const float*)d_in[9];   // [2,512]
  const float* egw  = (const float*)d_in[10];  // [8,512]
  const float* gb   = (const float*)d_in[11];  // [2]
  const float* eb   = (const float*)d_in[12];  // [8]
  float* out = (float*)d_out;

  // workspace layout (bytes)
  char* ws = (char*)d_ws;
  __bf16* w1   = (__bf16*)(ws);                 //  4,194,304  [4096,512]
  __bf16* w2   = (__bf16*)(ws + 4194304);       //  9,437,184  [9,512,1024]
  __bf16* lnb  = (__bf16*)(ws + 13631488);      //  8,388,608  [8192,512]
  __bf16* Hbuf = (__bf16*)(ws + 22020096);      // 33,554,432  [8192,2048]
  float*  comb = (float*)(ws + 55574528);       //    262,144  [8192,8]
  int*    tok  = (int*)(ws + 55836672);         //    262,144  [8,8192]
  int*    cnt  = (int*)(ws + 56098816);         //         32  [8]
  int*    off  = (int*)(ws + 56098848);         //         64  [9]
  // total: 56,098,912 bytes

  // 1) fused LN+gating+bias-init (blocks 0..2047) and weight cvt (2048..8703)
  ln_gate_cvt<<<8704, 256, 0, stream>>>(x, lns, lnbi, ggw, egw, gb, eb,
                                        sob, eob, siw, eiw, eow, sow,
                                        w1, w2, lnb, comb, out);

  // 2) routing lists + tile prefix (single block; no memset needed)
  route_build<<<1, 1024, 0, stream>>>(comb, cnt, tok, off);

  // 3) GEMM1 + SwiGLU (128x128-h tile, BK=64) -> H [8192,2048] bf16
  gemm1_swiglu<<<dim3(S_TOT / 128, 2 * H_DIM / 128), 256, 0, stream>>>(lnb, w1, Hbuf);

  // 4) compacted GEMM2 (R4 form: BK=64, single buffer)
  gemm2_moe<<<dim3(MAX_ETILES + 64, C_DIM / 128), 256, 0, stream>>>(
      Hbuf, w2, comb, cnt, tok, off, out);
}

// Round 8
// 239.931 us; speedup vs baseline: 1.1080x; 1.1080x over previous
//
#include <hip/hip_runtime.h>
#include <hip/hip_bf16.h>
#include <cstdint>

// ---------------------------------------------------------------------------
// HierDSFeedForward: LN -> shared SwiGLU FFN + hierarchical top-2 MoE
// S=8192 tokens, C=512, H=1024, G=2 groups x EG=4 experts, K=2
// R7: exact R4 launch structure (measured best) + atomic-free gemm2:
//     expert tiles -> compact Eo[16384,512] plain stores; shared tiles ->
//     single-writer RMW of out; new combine kernel sums per-token slots.
//     13.1M cross-XCD atomicAdds eliminated.
// ---------------------------------------------------------------------------

typedef __bf16 bf16x8 __attribute__((ext_vector_type(8)));
typedef __bf16 bf16x4 __attribute__((ext_vector_type(4)));
typedef float  f32x4  __attribute__((ext_vector_type(4)));

#define S_TOT 8192
#define C_DIM 512
#define H_DIM 1024
// max expert M-tiles: sum_e ceil(cnt_e/128) <= 16384/128 + 8 = 136
#define MAX_ETILES 136

// async global->LDS, 16B per lane. Per-lane GLOBAL address may scatter;
// LDS dest is wave-uniform base + lane*16.
__device__ __forceinline__ void gload_lds16(const void* g, void* l) {
  __builtin_amdgcn_global_load_lds(
      (__attribute__((address_space(1))) void*)(void*)(g),
      (__attribute__((address_space(3))) void*)(l),
      16, 0, 0);
}

// ---------------------------------------------------------------------------
// fused fp32 -> bf16 conversion for all weights, 4 elems/thread.
// dst layout: w1 = [siw(1M) | eiw(1M)], w2 = [eow(4M) | sow(0.5M)]
__global__ __launch_bounds__(256) void cvt_fused(
    const float* __restrict__ siw, const float* __restrict__ eiw,
    const float* __restrict__ eow, const float* __restrict__ sow,
    __bf16* __restrict__ w1, __bf16* __restrict__ w2) {
  const int i = (blockIdx.x * 256 + threadIdx.x) * 4;
  const float* src;
  __bf16* dst;
  if (i < 2097152) {  // w1
    src = (i < 1048576) ? (siw + i) : (eiw + (i - 1048576));
    dst = w1 + i;
  } else {            // w2
    const int j = i - 2097152;
    src = (j < 4194304) ? (eow + j) : (sow + (j - 4194304));
    dst = w2 + j;
  }
  float4 v = *(const float4*)src;
  bf16x4 o;
  o[0] = (__bf16)v.x; o[1] = (__bf16)v.y; o[2] = (__bf16)v.z; o[3] = (__bf16)v.w;
  *(bf16x4*)dst = o;
}

// ---------------------------------------------------------------------------
// Wave-per-token LayerNorm + hierarchical gating + output bias init.
// 4 tokens per 256-thread block; each lane owns 8 contiguous channels.
__global__ __launch_bounds__(256) void ln_gate_wave(
    const float* __restrict__ x,
    const float* __restrict__ ln_scale, const float* __restrict__ ln_bias,
    const float* __restrict__ ggw,   // [2,512]
    const float* __restrict__ egw,   // [8,512]
    const float* __restrict__ gb,    // [2]
    const float* __restrict__ eb,    // [8]
    const float* __restrict__ sob,   // [512]
    const float* __restrict__ eob,   // [8,512]
    __bf16* __restrict__ lnb,        // [8192,512] bf16 LN output
    float* __restrict__ comb,        // [8192,8] dense top-2 weights
    float* __restrict__ out)         // [8192,512] init: biases
{
  const int wave = threadIdx.x >> 6, lane = threadIdx.x & 63;
  const int s = blockIdx.x * 4 + wave;
  const size_t rowb = (size_t)s * C_DIM;
  const int c0 = lane * 8;

  const float4 va = *(const float4*)(x + rowb + c0);
  const float4 vb = *(const float4*)(x + rowb + c0 + 4);
  float v[8] = {va.x, va.y, va.z, va.w, vb.x, vb.y, vb.z, vb.w};

  float sum = 0.f;
#pragma unroll
  for (int j = 0; j < 8; j++) sum += v[j];
#pragma unroll
  for (int o = 1; o < 64; o <<= 1) sum += __shfl_xor(sum, o, 64);
  const float mu = sum * (1.0f / 512.0f);

  float sq = 0.f;
#pragma unroll
  for (int j = 0; j < 8; j++) { const float d = v[j] - mu; sq += d * d; }
#pragma unroll
  for (int o = 1; o < 64; o <<= 1) sq += __shfl_xor(sq, o, 64);
  const float rs = rsqrtf(sq * (1.0f / 512.0f) + 1e-5f);

  const float4 sa = *(const float4*)(ln_scale + c0);
  const float4 sb = *(const float4*)(ln_scale + c0 + 4);
  const float4 ba = *(const float4*)(ln_bias + c0);
  const float4 bb = *(const float4*)(ln_bias + c0 + 4);
  const float sc[8] = {sa.x, sa.y, sa.z, sa.w, sb.x, sb.y, sb.z, sb.w};
  const float bi[8] = {ba.x, ba.y, ba.z, ba.w, bb.x, bb.y, bb.z, bb.w};

  float y[8];
  bf16x8 yb;
#pragma unroll
  for (int j = 0; j < 8; j++) {
    y[j] = (v[j] - mu) * rs * sc[j] + bi[j];
    yb[j] = (__bf16)y[j];
  }
  *(bf16x8*)(lnb + rowb + c0) = yb;

  double lg[10];
#pragma unroll
  for (int r = 0; r < 10; r++) {
    const float* W = (r < 2) ? (ggw + r * C_DIM + c0) : (egw + (r - 2) * C_DIM + c0);
    const float4 wa = *(const float4*)(W);
    const float4 wb = *(const float4*)(W + 4);
    const float w[8] = {wa.x, wa.y, wa.z, wa.w, wb.x, wb.y, wb.z, wb.w};
    double p = 0.0;
#pragma unroll
    for (int j = 0; j < 8; j++) p += (double)y[j] * (double)w[j];
    lg[r] = p;
  }
#pragma unroll
  for (int o = 1; o < 64; o <<= 1) {
#pragma unroll
    for (int r = 0; r < 10; r++) lg[r] += __shfl_xor(lg[r], o, 64);
  }

  const double g0 = lg[0] + (double)gb[0], g1 = lg[1] + (double)gb[1];
  const int g = (g1 > g0) ? 1 : 0;
  double el[4], mx = -1e300;
#pragma unroll
  for (int j = 0; j < 4; j++) {
    el[j] = lg[2 + g * 4 + j] + (double)eb[g * 4 + j];
    if (el[j] > mx) mx = el[j];
  }
  double pr[4], ps = 0.0;
#pragma unroll
  for (int j = 0; j < 4; j++) { pr[j] = exp(el[j] - mx); ps += pr[j]; }
  int i0 = 0;
#pragma unroll
  for (int j = 1; j < 4; j++) if (pr[j] > pr[i0]) i0 = j;
  int i1 = -1;
#pragma unroll
  for (int j = 0; j < 4; j++) {
    if (j == i0) continue;
    if (i1 < 0 || pr[j] > pr[i1]) i1 = j;
  }
  const double p0 = pr[i0] / ps, p1 = pr[i1] / ps;
  const double nrm = p0 + p1 + 1e-8;
  const int e0 = g * 4 + i0, e1 = g * 4 + i1;
  const float w0 = (float)(p0 / nrm), w1v = (float)(p1 / nrm);

  if (lane < 8)
    comb[(size_t)s * 8 + lane] = (lane == e0) ? w0 : ((lane == e1) ? w1v : 0.0f);

  const float* eb0 = eob + e0 * C_DIM + c0;
  const float* eb1 = eob + e1 * C_DIM + c0;
  float4 oa, ob;
  {
    const float4 za = *(const float4*)(sob + c0);
    const float4 zb = *(const float4*)(sob + c0 + 4);
    const float4 ea = *(const float4*)(eb0);
    const float4 ebv = *(const float4*)(eb0 + 4);
    const float4 fa = *(const float4*)(eb1);
    const float4 fb = *(const float4*)(eb1 + 4);
    oa.x = za.x + ea.x + fa.x; oa.y = za.y + ea.y + fa.y;
    oa.z = za.z + ea.z + fa.z; oa.w = za.w + ea.w + fa.w;
    ob.x = zb.x + ebv.x + fb.x; ob.y = zb.y + ebv.y + fb.y;
    ob.z = zb.z + ebv.z + fb.z; ob.w = zb.w + ebv.w + fb.w;
  }
  *(float4*)(out + rowb + c0) = oa;
  *(float4*)(out + rowb + c0 + 4) = ob;
}

// ---------------------------------------------------------------------------
// Expert-list build, block-aggregated (R4 form) + slot map emission.
// sm[s] = ((e0<<16)|pos0, (e1<<16)|pos1 or -1); pos is position within
// the expert's token list.
__global__ __launch_bounds__(256) void build_lists(
    const float* __restrict__ comb, int* __restrict__ cnt,
    int* __restrict__ tok, int2* __restrict__ sm) {
  __shared__ int lcnt[8], lbase[8];
  const int t = threadIdx.x;
  if (t < 8) lcnt[t] = 0;
  __syncthreads();
  const int s = blockIdx.x * 256 + t;
  const float* cr = comb + (size_t)s * 8;
  int e0 = -1, e1 = -1;
#pragma unroll
  for (int j = 0; j < 8; j++) {
    if (cr[j] != 0.0f) { if (e0 < 0) e0 = j; else e1 = j; }
  }
  const int l0 = atomicAdd(&lcnt[e0], 1);
  const int l1 = (e1 >= 0) ? atomicAdd(&lcnt[e1], 1) : 0;
  __syncthreads();
  if (t < 8) lbase[t] = atomicAdd(&cnt[t], lcnt[t]);
  __syncthreads();
  const int p0 = lbase[e0] + l0;
  tok[e0 * S_TOT + p0] = s;
  int smy = -1;
  if (e1 >= 0) {
    const int p1 = lbase[e1] + l1;
    tok[e1 * S_TOT + p1] = s;
    smy = (e1 << 16) | p1;
  }
  sm[s] = make_int2((e0 << 16) | p0, smy);
}

// ---------------------------------------------------------------------------
// tile prefix (off, in 128-row tiles) + token prefix (toff, in tokens)
__global__ void prefix_tiles(const int* __restrict__ cnt, int* __restrict__ off,
                             int* __restrict__ toff) {
  int s = 0, ts = 0;
#pragma unroll
  for (int e = 0; e < 8; e++) {
    off[e] = s;  s  += (cnt[e] + 127) >> 7;
    toff[e] = ts; ts += cnt[e];
  }
  off[8] = s; toff[8] = ts;
}

// ---------------------------------------------------------------------------
// GEMM1 + fused SwiGLU (R4/R2 form: BK=32, 128x64-h tile).
__global__ __launch_bounds__(256) void gemm1_swiglu(
    const __bf16* __restrict__ A,
    const __bf16* __restrict__ W1,
    __bf16* __restrict__ H)
{
  constexpr int K = C_DIM;  // 512
  __shared__ __bf16 As[128 * 32];
  __shared__ __bf16 Bas[64 * 32];
  __shared__ __bf16 Bbs[64 * 32];

  const int m0 = blockIdx.x * 128;
  const int nh = blockIdx.y * 64;
  const int arow0 = nh + (nh < 1024 ? 0 : 1024);
  const int brow0 = arow0 + 1024;

  const int tid = threadIdx.x, wave = tid >> 6, lane = tid & 63;
  const int wrow = wave >> 1, wcol = wave & 1;
  const int lr16 = lane >> 2;
  const int lc   = (lane & 3) * 8;
  const int fm   = lane & 15;
  const int fq   = (lane >> 4) * 8;

  f32x4 acca[4][2] = {};
  f32x4 accb[4][2] = {};

  for (int k0 = 0; k0 < K; k0 += 32) {
#pragma unroll
    for (int i = 0; i < 2; i++) {
      const int rb = wave * 2 + i;
      gload_lds16(A + (size_t)(m0 + rb * 16 + lr16) * K + k0 + lc, As + rb * 512);
    }
    gload_lds16(W1 + (size_t)(arow0 + wave * 16 + lr16) * K + k0 + lc, Bas + wave * 512);
    gload_lds16(W1 + (size_t)(brow0 + wave * 16 + lr16) * K + k0 + lc, Bbs + wave * 512);
    __syncthreads();

    bf16x8 af[4], ba[2], bb[2];
#pragma unroll
    for (int mi = 0; mi < 4; mi++)
      af[mi] = *(const bf16x8*)&As[(wrow * 64 + mi * 16 + fm) * 32 + fq];
#pragma unroll
    for (int ni = 0; ni < 2; ni++) {
      const int r = wcol * 32 + ni * 16 + fm;
      ba[ni] = *(const bf16x8*)&Bas[r * 32 + fq];
      bb[ni] = *(const bf16x8*)&Bbs[r * 32 + fq];
    }
#pragma unroll
    for (int mi = 0; mi < 4; mi++) {
#pragma unroll
      for (int ni = 0; ni < 2; ni++) {
        acca[mi][ni] = __builtin_amdgcn_mfma_f32_16x16x32_bf16(af[mi], ba[ni], acca[mi][ni], 0, 0, 0);
        accb[mi][ni] = __builtin_amdgcn_mfma_f32_16x16x32_bf16(af[mi], bb[ni], accb[mi][ni], 0, 0, 0);
      }
    }
    __syncthreads();
  }

#pragma unroll
  for (int mi = 0; mi < 4; mi++) {
    const int row0 = m0 + wrow * 64 + mi * 16 + ((lane >> 4) << 2);
#pragma unroll
    for (int ni = 0; ni < 2; ni++) {
      const int c = nh + wcol * 32 + ni * 16 + fm;
#pragma unroll
      for (int r = 0; r < 4; r++) {
        const float a = acca[mi][ni][r];
        const float b = accb[mi][ni][r];
        const float sv = a / (1.0f + __expf(-a));
        H[(size_t)(row0 + r) * (2 * H_DIM) + c] = (__bf16)(sv * b);
      }
    }
  }
}

// ---------------------------------------------------------------------------
// Unified GEMM2 (R4 K-loop: BK=64 two-panel, single buffer).
// Epilogue (compact=1): expert tiles -> plain stores of scale*acc into
// Eo[toff[e]+m0+row, :]; shared tiles -> single-writer out += acc.
// Epilogue (compact=0): R4 atomic fallback.
__global__ __launch_bounds__(256) void gemm2_moe(
    const __bf16* __restrict__ Hb,   // [8192, 2048]
    const __bf16* __restrict__ W2,   // [9, 512, 1024]
    const float* __restrict__ comb,  // [8192, 8]
    const int* __restrict__ cnt,     // [8]
    const int* __restrict__ tok,     // [8, 8192]
    const int* __restrict__ off,     // [9] tile prefix
    const int* __restrict__ toff,    // [9] token prefix
    float* __restrict__ Eo,          // [16384, 512] compact expert outputs
    float* __restrict__ out,         // [8192, 512]
    int compact)
{
  constexpr int K = H_DIM;  // 1024
  __shared__ __bf16 As[2 * 128 * 32];   // [panel][row][32]
  __shared__ __bf16 Bs[2 * 128 * 32];
  __shared__ int tokLDS[128];

  const int g = blockIdx.x;
  const int T = off[8];
  int e, m0;
  if (g < T) {
    e = 0;
    while (e < 7 && g >= off[e + 1]) e++;
    m0 = (g - off[e]) * 128;
  } else if (g < T + 64) {
    e = 8;
    m0 = (g - T) * 128;
  } else {
    return;
  }
  const int cnt_e = (e == 8) ? S_TOT : cnt[e];
  const int n0 = blockIdx.y * 128;
  const __bf16* Bw = W2 + (size_t)e * C_DIM * H_DIM;
  const int abase = (e == 8) ? 0 : H_DIM;

  const int tid = threadIdx.x, wave = tid >> 6, lane = tid & 63;
  const int wrow = wave >> 1, wcol = wave & 1;
  const int lr16 = lane >> 2;
  const int lc   = (lane & 3) * 8;
  const int fm   = lane & 15;
  const int fq   = (lane >> 4) * 8;

  if (tid < 128) {
    const int r = m0 + tid;
    tokLDS[tid] = (e == 8) ? r : ((r < cnt_e) ? tok[e * S_TOT + r] : -1);
  }
  __syncthreads();

  const int row0 = wave * 32 + lr16;
  const int t0 = tokLDS[row0], t1 = tokLDS[row0 + 16];
  const __bf16* a0 = Hb + abase + (size_t)(t0 < 0 ? 0 : t0) * (2 * H_DIM) + lc;
  const __bf16* a1 = Hb + abase + (size_t)(t1 < 0 ? 0 : t1) * (2 * H_DIM) + lc;
  const __bf16* b0 = Bw + (size_t)(n0 + wave * 32 + lr16) * K + lc;
  const __bf16* b1 = Bw + (size_t)(n0 + wave * 32 + 16 + lr16) * K + lc;

  const int sA0 = wave * 1024;   // (wave*32)*32
  const int sA1 = sA0 + 512;

  f32x4 acc[4][4] = {};

  for (int k0 = 0; k0 < K; k0 += 64) {
    gload_lds16(a0 + k0,      As + sA0);
    gload_lds16(a0 + k0 + 32, As + 4096 + sA0);
    gload_lds16(a1 + k0,      As + sA1);
    gload_lds16(a1 + k0 + 32, As + 4096 + sA1);
    gload_lds16(b0 + k0,      Bs + sA0);
    gload_lds16(b0 + k0 + 32, Bs + 4096 + sA0);
    gload_lds16(b1 + k0,      Bs + sA1);
    gload_lds16(b1 + k0 + 32, Bs + 4096 + sA1);
    __syncthreads();

#pragma unroll
    for (int kc = 0; kc < 2; kc++) {
      bf16x8 af[4], bf[4];
#pragma unroll
      for (int mi = 0; mi < 4; mi++)
        af[mi] = *(const bf16x8*)&As[kc * 4096 + (wrow * 64 + mi * 16 + fm) * 32 + fq];
#pragma unroll
      for (int ni = 0; ni < 4; ni++)
        bf[ni] = *(const bf16x8*)&Bs[kc * 4096 + (wcol * 64 + ni * 16 + fm) * 32 + fq];
#pragma unroll
      for (int mi = 0; mi < 4; mi++)
#pragma unroll
        for (int ni = 0; ni < 4; ni++)
          acc[mi][ni] = __builtin_amdgcn_mfma_f32_16x16x32_bf16(af[mi], bf[ni], acc[mi][ni], 0, 0, 0);
    }
    __syncthreads();
  }

  const int toffE = (e < 8) ? toff[e] : 0;
#pragma unroll
  for (int mi = 0; mi < 4; mi++) {
    const int rbase = wrow * 64 + mi * 16 + ((lane >> 4) << 2);
#pragma unroll
    for (int r = 0; r < 4; r++) {
      const int rowIdx = rbase + r;
      const int token = tokLDS[rowIdx];
      if (token < 0) continue;
      if (compact) {
        if (e == 8) {
          // sole writer of this out patch: plain RMW
#pragma unroll
          for (int ni = 0; ni < 4; ni++) {
            const int c = n0 + wcol * 64 + ni * 16 + fm;
            float* p = &out[(size_t)token * C_DIM + c];
            *p = *p + acc[mi][ni][r];
          }
        } else {
          const float scale = comb[(size_t)token * 8 + e];
          float* dst = &Eo[(size_t)(toffE + m0 + rowIdx) * C_DIM];
#pragma unroll
          for (int ni = 0; ni < 4; ni++) {
            const int c = n0 + wcol * 64 + ni * 16 + fm;
            dst[c] = scale * acc[mi][ni][r];
          }
        }
      } else {
        const float scale = (e == 8) ? 1.0f : comb[(size_t)token * 8 + e];
        if (scale != 0.0f) {
#pragma unroll
          for (int ni = 0; ni < 4; ni++) {
            const int c = n0 + wcol * 64 + ni * 16 + fm;
            atomicAdd(&out[(size_t)token * C_DIM + c], scale * acc[mi][ni][r]);
          }
        }
      }
    }
  }
}

// ---------------------------------------------------------------------------
// Combine: out[s] += Eo[slot0] (+ Eo[slot1]). Wave per token, 4 tokens/block.
__global__ __launch_bounds__(256) void combine(
    const float* __restrict__ Eo, const int2* __restrict__ sm,
    const int* __restrict__ toff, float* __restrict__ out) {
  const int wave = threadIdx.x >> 6, lane = threadIdx.x & 63;
  const int s = blockIdx.x * 4 + wave;
  const int c0 = lane * 8;
  const int2 m = sm[s];
  const int e0 = m.x >> 16, p0 = m.x & 0xffff;
  const float* src0 = Eo + (size_t)(toff[e0] + p0) * C_DIM + c0;
  float4 v0 = *(const float4*)(src0);
  float4 v1 = *(const float4*)(src0 + 4);
  if (m.y >= 0) {
    const int e1 = m.y >> 16, p1 = m.y & 0xffff;
    const float* src1 = Eo + (size_t)(toff[e1] + p1) * C_DIM + c0;
    const float4 w0 = *(const float4*)(src1);
    const float4 w1 = *(const float4*)(src1 + 4);
    v0.x += w0.x; v0.y += w0.y; v0.z += w0.z; v0.w += w0.w;
    v1.x += w1.x; v1.y += w1.y; v1.z += w1.z; v1.w += w1.w;
  }
  float* dst = out + (size_t)s * C_DIM + c0;
  float4 o0 = *(const float4*)(dst);
  float4 o1 = *(const float4*)(dst + 4);
  o0.x += v0.x; o0.y += v0.y; o0.z += v0.z; o0.w += v0.w;
  o1.x += v1.x; o1.y += v1.y; o1.z += v1.z; o1.w += v1.w;
  *(float4*)(dst) = o0;
  *(float4*)(dst + 4) = o1;
}

// ---------------------------------------------------------------------------
extern "C" void kernel_launch(void* const* d_in, const int* in_sizes, int n_in,
                              void* d_out, int out_size, void* d_ws, size_t ws_size,
                              hipStream_t stream) {
  const float* x    = (const float*)d_in[0];
  const float* lns  = (const float*)d_in[1];
  const float* lnbi = (const float*)d_in[2];
  const float* siw  = (const float*)d_in[3];   // [2048,512]
  const float* sow  = (const float*)d_in[4];   // [512,1024]
  const float* sob  = (const float*)d_in[5];   // [512]
  const float* eiw  = (const float*)d_in[6];   // [2048,512]
  const float* eow  = (const float*)d_in[7];   // [8,512,1024]
  const float* eob  = (const float*)d_in[8];   // [8,512]
  const float* ggw  = (const float*)d_in[9];   // [2,512]
  const float* egw  = (const float*)d_in[10];  // [8,512]
  const float* gb   = (const float*)d_in[11];  // [2]
  const float* eb   = (const float*)d_in[12];  // [8]
  float* out = (float*)d_out;

  // workspace layout (bytes)
  char* ws = (char*)d_ws;
  __bf16* w1   = (__bf16*)(ws);                 //  4,194,304  [4096,512]
  __bf16* w2   = (__bf16*)(ws + 4194304);       //  9,437,184  [9,512,1024]
  __bf16* lnb  = (__bf16*)(ws + 13631488);      //  8,388,608  [8192,512]
  __bf16* Hbuf = (__bf16*)(ws + 22020096);      // 33,554,432  [8192,2048]
  float*  comb = (float*)(ws + 55574528);       //    262,144  [8192,8]
  int*    tok  = (int*)(ws + 55836672);         //    262,144  [8,8192]
  int2*   sm   = (int2*)(ws + 56098816);        //     65,536  [8192]
  int*    cnt  = (int*)(ws + 56164352);         //         32  [8]
  int*    off  = (int*)(ws + 56164384);         //         64  [9]
  int*    toff = (int*)(ws + 56164448);         //         64  [9]
  float*  Eo   = (float*)(ws + 56164512);       // 33,554,432  [16384,512]
  const size_t NEED = 89718944;
  const int compact = (ws_size >= NEED) ? 1 : 0;

  hipMemsetAsync(cnt, 0, 32, stream);

  // 1) weight conversion fp32->bf16
  cvt_fused<<<6656, 256, 0, stream>>>(siw, eiw, eow, sow, w1, w2);

  // 2) LayerNorm + gating + bias init (wave per token)
  ln_gate_wave<<<S_TOT / 4, 256, 0, stream>>>(x, lns, lnbi, ggw, egw, gb, eb,
                                              sob, eob, lnb, comb, out);

  // 3) expert lists + slot map, then tile/token prefixes
  build_lists<<<S_TOT / 256, 256, 0, stream>>>(comb, cnt, tok, sm);
  prefix_tiles<<<1, 1, 0, stream>>>(cnt, off, toff);

  // 4) GEMM1 + SwiGLU -> H [8192,2048] bf16
  gemm1_swiglu<<<dim3(S_TOT / 128, 2 * H_DIM / 64), 256, 0, stream>>>(lnb, w1, Hbuf);

  // 5) compacted GEMM2 (atomic-free when ws allows)
  gemm2_moe<<<dim3(MAX_ETILES + 64, C_DIM / 128), 256, 0, stream>>>(
      Hbuf, w2, comb, cnt, tok, off, toff, Eo, out, compact);

  // 6) per-token combine of the two expert slots
  if (compact)
    combine<<<S_TOT / 4, 256, 0, stream>>>(Eo, sm, toff, out);
}

// Round 9
// 236.131 us; speedup vs baseline: 1.1258x; 1.0161x over previous
//
#include <hip/hip_runtime.h>
#include <hip/hip_bf16.h>
#include <cstdint>

// ---------------------------------------------------------------------------
// HierDSFeedForward: LN -> shared SwiGLU FFN + hierarchical top-2 MoE
// S=8192 tokens, C=512, H=1024, G=2 groups x EG=4 experts, K=2
// R8: gemm2 is HBM-traffic-bound (139 MB @ 2.4 TB/s == 59 us identity).
//     Cut traffic: Eo -> bf16 (expert slots + shared slab); gemm2 no longer
//     RMWs `out`; combine does the single out RMW (bias + sh + 2 slots).
// ---------------------------------------------------------------------------

typedef __bf16 bf16x8 __attribute__((ext_vector_type(8)));
typedef __bf16 bf16x4 __attribute__((ext_vector_type(4)));
typedef float  f32x4  __attribute__((ext_vector_type(4)));

#define S_TOT 8192
#define C_DIM 512
#define H_DIM 1024
// max expert M-tiles: sum_e ceil(cnt_e/128) <= 16384/128 + 8 = 136
#define MAX_ETILES 136

// async global->LDS, 16B per lane. Per-lane GLOBAL address may scatter;
// LDS dest is wave-uniform base + lane*16.
__device__ __forceinline__ void gload_lds16(const void* g, void* l) {
  __builtin_amdgcn_global_load_lds(
      (__attribute__((address_space(1))) void*)(void*)(g),
      (__attribute__((address_space(3))) void*)(l),
      16, 0, 0);
}

// ---------------------------------------------------------------------------
// fused fp32 -> bf16 conversion for all weights, 4 elems/thread.
// dst layout: w1 = [siw(1M) | eiw(1M)], w2 = [eow(4M) | sow(0.5M)]
__global__ __launch_bounds__(256) void cvt_fused(
    const float* __restrict__ siw, const float* __restrict__ eiw,
    const float* __restrict__ eow, const float* __restrict__ sow,
    __bf16* __restrict__ w1, __bf16* __restrict__ w2) {
  const int i = (blockIdx.x * 256 + threadIdx.x) * 4;
  const float* src;
  __bf16* dst;
  if (i < 2097152) {  // w1
    src = (i < 1048576) ? (siw + i) : (eiw + (i - 1048576));
    dst = w1 + i;
  } else {            // w2
    const int j = i - 2097152;
    src = (j < 4194304) ? (eow + j) : (sow + (j - 4194304));
    dst = w2 + j;
  }
  float4 v = *(const float4*)src;
  bf16x4 o;
  o[0] = (__bf16)v.x; o[1] = (__bf16)v.y; o[2] = (__bf16)v.z; o[3] = (__bf16)v.w;
  *(bf16x4*)dst = o;
}

// ---------------------------------------------------------------------------
// Wave-per-token LayerNorm + hierarchical gating + output bias init.
// 4 tokens per 256-thread block; each lane owns 8 contiguous channels.
__global__ __launch_bounds__(256) void ln_gate_wave(
    const float* __restrict__ x,
    const float* __restrict__ ln_scale, const float* __restrict__ ln_bias,
    const float* __restrict__ ggw,   // [2,512]
    const float* __restrict__ egw,   // [8,512]
    const float* __restrict__ gb,    // [2]
    const float* __restrict__ eb,    // [8]
    const float* __restrict__ sob,   // [512]
    const float* __restrict__ eob,   // [8,512]
    __bf16* __restrict__ lnb,        // [8192,512] bf16 LN output
    float* __restrict__ comb,        // [8192,8] dense top-2 weights
    float* __restrict__ out)         // [8192,512] init: biases
{
  const int wave = threadIdx.x >> 6, lane = threadIdx.x & 63;
  const int s = blockIdx.x * 4 + wave;
  const size_t rowb = (size_t)s * C_DIM;
  const int c0 = lane * 8;

  const float4 va = *(const float4*)(x + rowb + c0);
  const float4 vb = *(const float4*)(x + rowb + c0 + 4);
  float v[8] = {va.x, va.y, va.z, va.w, vb.x, vb.y, vb.z, vb.w};

  float sum = 0.f;
#pragma unroll
  for (int j = 0; j < 8; j++) sum += v[j];
#pragma unroll
  for (int o = 1; o < 64; o <<= 1) sum += __shfl_xor(sum, o, 64);
  const float mu = sum * (1.0f / 512.0f);

  float sq = 0.f;
#pragma unroll
  for (int j = 0; j < 8; j++) { const float d = v[j] - mu; sq += d * d; }
#pragma unroll
  for (int o = 1; o < 64; o <<= 1) sq += __shfl_xor(sq, o, 64);
  const float rs = rsqrtf(sq * (1.0f / 512.0f) + 1e-5f);

  const float4 sa = *(const float4*)(ln_scale + c0);
  const float4 sb = *(const float4*)(ln_scale + c0 + 4);
  const float4 ba = *(const float4*)(ln_bias + c0);
  const float4 bb = *(const float4*)(ln_bias + c0 + 4);
  const float sc[8] = {sa.x, sa.y, sa.z, sa.w, sb.x, sb.y, sb.z, sb.w};
  const float bi[8] = {ba.x, ba.y, ba.z, ba.w, bb.x, bb.y, bb.z, bb.w};

  float y[8];
  bf16x8 yb;
#pragma unroll
  for (int j = 0; j < 8; j++) {
    y[j] = (v[j] - mu) * rs * sc[j] + bi[j];
    yb[j] = (__bf16)y[j];
  }
  *(bf16x8*)(lnb + rowb + c0) = yb;

  double lg[10];
#pragma unroll
  for (int r = 0; r < 10; r++) {
    const float* W = (r < 2) ? (ggw + r * C_DIM + c0) : (egw + (r - 2) * C_DIM + c0);
    const float4 wa = *(const float4*)(W);
    const float4 wb = *(const float4*)(W + 4);
    const float w[8] = {wa.x, wa.y, wa.z, wa.w, wb.x, wb.y, wb.z, wb.w};
    double p = 0.0;
#pragma unroll
    for (int j = 0; j < 8; j++) p += (double)y[j] * (double)w[j];
    lg[r] = p;
  }
#pragma unroll
  for (int o = 1; o < 64; o <<= 1) {
#pragma unroll
    for (int r = 0; r < 10; r++) lg[r] += __shfl_xor(lg[r], o, 64);
  }

  const double g0 = lg[0] + (double)gb[0], g1 = lg[1] + (double)gb[1];
  const int g = (g1 > g0) ? 1 : 0;
  double el[4], mx = -1e300;
#pragma unroll
  for (int j = 0; j < 4; j++) {
    el[j] = lg[2 + g * 4 + j] + (double)eb[g * 4 + j];
    if (el[j] > mx) mx = el[j];
  }
  double pr[4], ps = 0.0;
#pragma unroll
  for (int j = 0; j < 4; j++) { pr[j] = exp(el[j] - mx); ps += pr[j]; }
  int i0 = 0;
#pragma unroll
  for (int j = 1; j < 4; j++) if (pr[j] > pr[i0]) i0 = j;
  int i1 = -1;
#pragma unroll
  for (int j = 0; j < 4; j++) {
    if (j == i0) continue;
    if (i1 < 0 || pr[j] > pr[i1]) i1 = j;
  }
  const double p0 = pr[i0] / ps, p1 = pr[i1] / ps;
  const double nrm = p0 + p1 + 1e-8;
  const int e0 = g * 4 + i0, e1 = g * 4 + i1;
  const float w0 = (float)(p0 / nrm), w1v = (float)(p1 / nrm);

  if (lane < 8)
    comb[(size_t)s * 8 + lane] = (lane == e0) ? w0 : ((lane == e1) ? w1v : 0.0f);

  const float* eb0 = eob + e0 * C_DIM + c0;
  const float* eb1 = eob + e1 * C_DIM + c0;
  float4 oa, ob;
  {
    const float4 za = *(const float4*)(sob + c0);
    const float4 zb = *(const float4*)(sob + c0 + 4);
    const float4 ea = *(const float4*)(eb0);
    const float4 ebv = *(const float4*)(eb0 + 4);
    const float4 fa = *(const float4*)(eb1);
    const float4 fb = *(const float4*)(eb1 + 4);
    oa.x = za.x + ea.x + fa.x; oa.y = za.y + ea.y + fa.y;
    oa.z = za.z + ea.z + fa.z; oa.w = za.w + ea.w + fa.w;
    ob.x = zb.x + ebv.x + fb.x; ob.y = zb.y + ebv.y + fb.y;
    ob.z = zb.z + ebv.z + fb.z; ob.w = zb.w + ebv.w + fb.w;
  }
  *(float4*)(out + rowb + c0) = oa;
  *(float4*)(out + rowb + c0 + 4) = ob;
}

// ---------------------------------------------------------------------------
// Expert-list build, block-aggregated + slot map emission.
// sm[s] = ((e0<<16)|pos0, (e1<<16)|pos1 or -1).
__global__ __launch_bounds__(256) void build_lists(
    const float* __restrict__ comb, int* __restrict__ cnt,
    int* __restrict__ tok, int2* __restrict__ sm) {
  __shared__ int lcnt[8], lbase[8];
  const int t = threadIdx.x;
  if (t < 8) lcnt[t] = 0;
  __syncthreads();
  const int s = blockIdx.x * 256 + t;
  const float* cr = comb + (size_t)s * 8;
  int e0 = -1, e1 = -1;
#pragma unroll
  for (int j = 0; j < 8; j++) {
    if (cr[j] != 0.0f) { if (e0 < 0) e0 = j; else e1 = j; }
  }
  const int l0 = atomicAdd(&lcnt[e0], 1);
  const int l1 = (e1 >= 0) ? atomicAdd(&lcnt[e1], 1) : 0;
  __syncthreads();
  if (t < 8) lbase[t] = atomicAdd(&cnt[t], lcnt[t]);
  __syncthreads();
  const int p0 = lbase[e0] + l0;
  tok[e0 * S_TOT + p0] = s;
  int smy = -1;
  if (e1 >= 0) {
    const int p1 = lbase[e1] + l1;
    tok[e1 * S_TOT + p1] = s;
    smy = (e1 << 16) | p1;
  }
  sm[s] = make_int2((e0 << 16) | p0, smy);
}

// ---------------------------------------------------------------------------
// tile prefix (off, in 128-row tiles) + token prefix (toff, in tokens)
__global__ void prefix_tiles(const int* __restrict__ cnt, int* __restrict__ off,
                             int* __restrict__ toff) {
  int s = 0, ts = 0;
#pragma unroll
  for (int e = 0; e < 8; e++) {
    off[e] = s;  s  += (cnt[e] + 127) >> 7;
    toff[e] = ts; ts += cnt[e];
  }
  off[8] = s; toff[8] = ts;
}

// ---------------------------------------------------------------------------
// GEMM1 + fused SwiGLU (BK=32, 128x64-h tile).
__global__ __launch_bounds__(256) void gemm1_swiglu(
    const __bf16* __restrict__ A,
    const __bf16* __restrict__ W1,
    __bf16* __restrict__ H)
{
  constexpr int K = C_DIM;  // 512
  __shared__ __bf16 As[128 * 32];
  __shared__ __bf16 Bas[64 * 32];
  __shared__ __bf16 Bbs[64 * 32];

  const int m0 = blockIdx.x * 128;
  const int nh = blockIdx.y * 64;
  const int arow0 = nh + (nh < 1024 ? 0 : 1024);
  const int brow0 = arow0 + 1024;

  const int tid = threadIdx.x, wave = tid >> 6, lane = tid & 63;
  const int wrow = wave >> 1, wcol = wave & 1;
  const int lr16 = lane >> 2;
  const int lc   = (lane & 3) * 8;
  const int fm   = lane & 15;
  const int fq   = (lane >> 4) * 8;

  f32x4 acca[4][2] = {};
  f32x4 accb[4][2] = {};

  for (int k0 = 0; k0 < K; k0 += 32) {
#pragma unroll
    for (int i = 0; i < 2; i++) {
      const int rb = wave * 2 + i;
      gload_lds16(A + (size_t)(m0 + rb * 16 + lr16) * K + k0 + lc, As + rb * 512);
    }
    gload_lds16(W1 + (size_t)(arow0 + wave * 16 + lr16) * K + k0 + lc, Bas + wave * 512);
    gload_lds16(W1 + (size_t)(brow0 + wave * 16 + lr16) * K + k0 + lc, Bbs + wave * 512);
    __syncthreads();

    bf16x8 af[4], ba[2], bb[2];
#pragma unroll
    for (int mi = 0; mi < 4; mi++)
      af[mi] = *(const bf16x8*)&As[(wrow * 64 + mi * 16 + fm) * 32 + fq];
#pragma unroll
    for (int ni = 0; ni < 2; ni++) {
      const int r = wcol * 32 + ni * 16 + fm;
      ba[ni] = *(const bf16x8*)&Bas[r * 32 + fq];
      bb[ni] = *(const bf16x8*)&Bbs[r * 32 + fq];
    }
#pragma unroll
    for (int mi = 0; mi < 4; mi++) {
#pragma unroll
      for (int ni = 0; ni < 2; ni++) {
        acca[mi][ni] = __builtin_amdgcn_mfma_f32_16x16x32_bf16(af[mi], ba[ni], acca[mi][ni], 0, 0, 0);
        accb[mi][ni] = __builtin_amdgcn_mfma_f32_16x16x32_bf16(af[mi], bb[ni], accb[mi][ni], 0, 0, 0);
      }
    }
    __syncthreads();
  }

#pragma unroll
  for (int mi = 0; mi < 4; mi++) {
    const int row0 = m0 + wrow * 64 + mi * 16 + ((lane >> 4) << 2);
#pragma unroll
    for (int ni = 0; ni < 2; ni++) {
      const int c = nh + wcol * 32 + ni * 16 + fm;
#pragma unroll
      for (int r = 0; r < 4; r++) {
        const float a = acca[mi][ni][r];
        const float b = accb[mi][ni][r];
        const float sv = a / (1.0f + __expf(-a));
        H[(size_t)(row0 + r) * (2 * H_DIM) + c] = (__bf16)(sv * b);
      }
    }
  }
}

// ---------------------------------------------------------------------------
// Unified GEMM2 (BK=64 two-panel, single buffer).
// Epilogue (compact=1): expert tiles -> bf16 stores of scale*acc into
// Eo[toff[e]+m0+row, :]; shared tiles -> bf16 stores into Eo[16384+token, :].
// gemm2 never touches `out`. (compact=0): atomic fallback into out.
__global__ __launch_bounds__(256) void gemm2_moe(
    const __bf16* __restrict__ Hb,   // [8192, 2048]
    const __bf16* __restrict__ W2,   // [9, 512, 1024]
    const float* __restrict__ comb,  // [8192, 8]
    const int* __restrict__ cnt,     // [8]
    const int* __restrict__ tok,     // [8, 8192]
    const int* __restrict__ off,     // [9] tile prefix
    const int* __restrict__ toff,    // [9] token prefix
    __bf16* __restrict__ Eo,         // [24576, 512] bf16 compact outputs
    float* __restrict__ out,         // [8192, 512] (fallback only)
    int compact)
{
  constexpr int K = H_DIM;  // 1024
  __shared__ __bf16 As[2 * 128 * 32];   // [panel][row][32]
  __shared__ __bf16 Bs[2 * 128 * 32];
  __shared__ int tokLDS[128];

  const int g = blockIdx.x;
  const int T = off[8];
  int e, m0;
  if (g < T) {
    e = 0;
    while (e < 7 && g >= off[e + 1]) e++;
    m0 = (g - off[e]) * 128;
  } else if (g < T + 64) {
    e = 8;
    m0 = (g - T) * 128;
  } else {
    return;
  }
  const int cnt_e = (e == 8) ? S_TOT : cnt[e];
  const int n0 = blockIdx.y * 128;
  const __bf16* Bw = W2 + (size_t)e * C_DIM * H_DIM;
  const int abase = (e == 8) ? 0 : H_DIM;

  const int tid = threadIdx.x, wave = tid >> 6, lane = tid & 63;
  const int wrow = wave >> 1, wcol = wave & 1;
  const int lr16 = lane >> 2;
  const int lc   = (lane & 3) * 8;
  const int fm   = lane & 15;
  const int fq   = (lane >> 4) * 8;

  if (tid < 128) {
    const int r = m0 + tid;
    tokLDS[tid] = (e == 8) ? r : ((r < cnt_e) ? tok[e * S_TOT + r] : -1);
  }
  __syncthreads();

  const int row0 = wave * 32 + lr16;
  const int t0 = tokLDS[row0], t1 = tokLDS[row0 + 16];
  const __bf16* a0 = Hb + abase + (size_t)(t0 < 0 ? 0 : t0) * (2 * H_DIM) + lc;
  const __bf16* a1 = Hb + abase + (size_t)(t1 < 0 ? 0 : t1) * (2 * H_DIM) + lc;
  const __bf16* b0 = Bw + (size_t)(n0 + wave * 32 + lr16) * K + lc;
  const __bf16* b1 = Bw + (size_t)(n0 + wave * 32 + 16 + lr16) * K + lc;

  const int sA0 = wave * 1024;   // (wave*32)*32
  const int sA1 = sA0 + 512;

  f32x4 acc[4][4] = {};

  for (int k0 = 0; k0 < K; k0 += 64) {
    gload_lds16(a0 + k0,      As + sA0);
    gload_lds16(a0 + k0 + 32, As + 4096 + sA0);
    gload_lds16(a1 + k0,      As + sA1);
    gload_lds16(a1 + k0 + 32, As + 4096 + sA1);
    gload_lds16(b0 + k0,      Bs + sA0);
    gload_lds16(b0 + k0 + 32, Bs + 4096 + sA0);
    gload_lds16(b1 + k0,      Bs + sA1);
    gload_lds16(b1 + k0 + 32, Bs + 4096 + sA1);
    __syncthreads();

#pragma unroll
    for (int kc = 0; kc < 2; kc++) {
      bf16x8 af[4], bf[4];
#pragma unroll
      for (int mi = 0; mi < 4; mi++)
        af[mi] = *(const bf16x8*)&As[kc * 4096 + (wrow * 64 + mi * 16 + fm) * 32 + fq];
#pragma unroll
      for (int ni = 0; ni < 4; ni++)
        bf[ni] = *(const bf16x8*)&Bs[kc * 4096 + (wcol * 64 + ni * 16 + fm) * 32 + fq];
#pragma unroll
      for (int mi = 0; mi < 4; mi++)
#pragma unroll
        for (int ni = 0; ni < 4; ni++)
          acc[mi][ni] = __builtin_amdgcn_mfma_f32_16x16x32_bf16(af[mi], bf[ni], acc[mi][ni], 0, 0, 0);
    }
    __syncthreads();
  }

  const int toffE = (e < 8) ? toff[e] : 0;
#pragma unroll
  for (int mi = 0; mi < 4; mi++) {
    const int rbase = wrow * 64 + mi * 16 + ((lane >> 4) << 2);
#pragma unroll
    for (int r = 0; r < 4; r++) {
      const int rowIdx = rbase + r;
      const int token = tokLDS[rowIdx];
      if (token < 0) continue;
      if (compact) {
        __bf16* dst;
        float scale;
        if (e == 8) {
          dst = &Eo[(size_t)(16384 + token) * C_DIM];
          scale = 1.0f;
        } else {
          dst = &Eo[(size_t)(toffE + m0 + rowIdx) * C_DIM];
          scale = comb[(size_t)token * 8 + e];
        }
#pragma unroll
        for (int ni = 0; ni < 4; ni++) {
          const int c = n0 + wcol * 64 + ni * 16 + fm;
          dst[c] = (__bf16)(scale * acc[mi][ni][r]);
        }
      } else {
        const float scale = (e == 8) ? 1.0f : comb[(size_t)token * 8 + e];
        if (scale != 0.0f) {
#pragma unroll
          for (int ni = 0; ni < 4; ni++) {
            const int c = n0 + wcol * 64 + ni * 16 + fm;
            atomicAdd(&out[(size_t)token * C_DIM + c], scale * acc[mi][ni][r]);
          }
        }
      }
    }
  }
}

// ---------------------------------------------------------------------------
// Combine: out[s](bias) += Eo_sh[s] + Eo[slot0] (+ Eo[slot1]).
// Wave per token, 4 tokens/block; bf16x8 loads, f32 accumulate.
__global__ __launch_bounds__(256) void combine(
    const __bf16* __restrict__ Eo, const int2* __restrict__ sm,
    const int* __restrict__ toff, float* __restrict__ out) {
  const int wave = threadIdx.x >> 6, lane = threadIdx.x & 63;
  const int s = blockIdx.x * 4 + wave;
  const int c0 = lane * 8;
  const int2 m = sm[s];
  const int e0 = m.x >> 16, p0 = m.x & 0xffff;

  const bf16x8 vs = *(const bf16x8*)(Eo + (size_t)(16384 + s) * C_DIM + c0);
  const bf16x8 v0 = *(const bf16x8*)(Eo + (size_t)(toff[e0] + p0) * C_DIM + c0);
  float accv[8];
#pragma unroll
  for (int j = 0; j < 8; j++) accv[j] = (float)vs[j] + (float)v0[j];
  if (m.y >= 0) {
    const int e1 = m.y >> 16, p1 = m.y & 0xffff;
    const bf16x8 v1 = *(const bf16x8*)(Eo + (size_t)(toff[e1] + p1) * C_DIM + c0);
#pragma unroll
    for (int j = 0; j < 8; j++) accv[j] += (float)v1[j];
  }
  float* dst = out + (size_t)s * C_DIM + c0;
  float4 o0 = *(const float4*)(dst);
  float4 o1 = *(const float4*)(dst + 4);
  o0.x += accv[0]; o0.y += accv[1]; o0.z += accv[2]; o0.w += accv[3];
  o1.x += accv[4]; o1.y += accv[5]; o1.z += accv[6]; o1.w += accv[7];
  *(float4*)(dst) = o0;
  *(float4*)(dst + 4) = o1;
}

// ---------------------------------------------------------------------------
extern "C" void kernel_launch(void* const* d_in, const int* in_sizes, int n_in,
                              void* d_out, int out_size, void* d_ws, size_t ws_size,
                              hipStream_t stream) {
  const float* x    = (const float*)d_in[0];
  const float* lns  = (const float*)d_in[1];
  const float* lnbi = (const float*)d_in[2];
  const float* siw  = (const float*)d_in[3];   // [2048,512]
  const float* sow  = (const float*)d_in[4];   // [512,1024]
  const float* sob  = (const float*)d_in[5];   // [512]
  const float* eiw  = (const float*)d_in[6];   // [2048,512]
  const float* eow  = (const float*)d_in[7];   // [8,512,1024]
  const float* eob  = (const float*)d_in[8];   // [8,512]
  const float* ggw  = (const float*)d_in[9];   // [2,512]
  const float* egw  = (const float*)d_in[10];  // [8,512]
  const float* gb   = (const float*)d_in[11];  // [2]
  const float* eb   = (const float*)d_in[12];  // [8]
  float* out = (float*)d_out;

  // workspace layout (bytes)
  char* ws = (char*)d_ws;
  __bf16* w1   = (__bf16*)(ws);                 //  4,194,304  [4096,512]
  __bf16* w2   = (__bf16*)(ws + 4194304);       //  9,437,184  [9,512,1024]
  __bf16* lnb  = (__bf16*)(ws + 13631488);      //  8,388,608  [8192,512]
  __bf16* Hbuf = (__bf16*)(ws + 22020096);      // 33,554,432  [8192,2048]
  float*  comb = (float*)(ws + 55574528);       //    262,144  [8192,8]
  int*    tok  = (int*)(ws + 55836672);         //    262,144  [8,8192]
  int2*   sm   = (int2*)(ws + 56098816);        //     65,536  [8192]
  int*    cnt  = (int*)(ws + 56164352);         //         32  [8]
  int*    off  = (int*)(ws + 56164384);         //         64  [9]
  int*    toff = (int*)(ws + 56164448);         //         64  [9]
  __bf16* Eo   = (__bf16*)(ws + 56164512);      // 25,165,824  [24576,512] bf16
  const size_t NEED = 81330336;
  const int compact = (ws_size >= NEED) ? 1 : 0;

  hipMemsetAsync(cnt, 0, 32, stream);

  // 1) weight conversion fp32->bf16
  cvt_fused<<<6656, 256, 0, stream>>>(siw, eiw, eow, sow, w1, w2);

  // 2) LayerNorm + gating + bias init (wave per token)
  ln_gate_wave<<<S_TOT / 4, 256, 0, stream>>>(x, lns, lnbi, ggw, egw, gb, eb,
                                              sob, eob, lnb, comb, out);

  // 3) expert lists + slot map, then tile/token prefixes
  build_lists<<<S_TOT / 256, 256, 0, stream>>>(comb, cnt, tok, sm);
  prefix_tiles<<<1, 1, 0, stream>>>(cnt, off, toff);

  // 4) GEMM1 + SwiGLU -> H [8192,2048] bf16
  gemm1_swiglu<<<dim3(S_TOT / 128, 2 * H_DIM / 64), 256, 0, stream>>>(lnb, w1, Hbuf);

  // 5) compacted GEMM2 (bf16 Eo, no out traffic)
  gemm2_moe<<<dim3(MAX_ETILES + 64, C_DIM / 128), 256, 0, stream>>>(
      Hbuf, w2, comb, cnt, tok, off, toff, Eo, out, compact);

  // 6) per-token combine: bias-out + shared + 2 expert slots
  if (compact)
    combine<<<S_TOT / 4, 256, 0, stream>>>(Eo, sm, toff, out);
}